// Round 11
// baseline (522.327 us; speedup 1.0000x reference)
//
#include <hip/hip_runtime.h>
#include <math.h>

#define B_ 2
#define S_ 2048
#define DIM_ 4096
#define H_ 32
#define KV_ 8
#define HD_ 128
#define SCALE_ 0.08838834764831844f   // 128^-0.5
#define QSCALE_ 0.12751744154254998f  // SCALE_ * log2(e)

typedef unsigned short u16;
typedef __attribute__((ext_vector_type(8))) short bf16x8;
typedef __attribute__((ext_vector_type(4))) float f32x4;
typedef __attribute__((ext_vector_type(16))) float f32x16;
typedef __attribute__((ext_vector_type(8))) unsigned short u16x8;
typedef __attribute__((ext_vector_type(4))) unsigned short u16x4;

__device__ __forceinline__ u16 f2b(float f) {  // RNE f32->bf16
  union { float f; unsigned u; } v; v.f = f;
  unsigned r = v.u + 0x7fffu + ((v.u >> 16) & 1u);
  return (u16)(r >> 16);
}
__device__ __forceinline__ float b2f(u16 h) {
  union { unsigned u; float f; } v; v.u = ((unsigned)h) << 16;
  return v.f;
}
// HW packed f32->bf16 (RNE): lo -> bits[15:0], hi -> bits[31:16]
__device__ __forceinline__ unsigned cvt_pk_bf16(float lo, float hi) {
  unsigned r;
  asm("v_cvt_pk_bf16_f32 %0, %1, %2" : "=v"(r) : "v"(lo), "v"(hi));
  return r;
}
// Direct-to-LDS async copy, 16B/lane. LDS dest = wave-uniform base + lane*16.
__device__ __forceinline__ void async_copy16(const void* g, void* l) {
  __builtin_amdgcn_global_load_lds(
      (const __attribute__((address_space(1))) void*)g,
      (__attribute__((address_space(3))) void*)l, 16, 0, 0);
}
// Raw barrier WITH compiler memory fence (no vmcnt drain, unlike __syncthreads)
__device__ __forceinline__ void bar() {
  asm volatile("s_barrier" ::: "memory");
}

// ---------------------------------------------------------------------------
// fp32 -> bf16 bulk convert (vectorized)
// ---------------------------------------------------------------------------
__global__ __launch_bounds__(256) void cvt_bf16(const float* __restrict__ in,
                                                u16* __restrict__ out, int n4) {
  int i = blockIdx.x * 256 + threadIdx.x;
  if (i >= n4) return;
  float4 v = ((const float4*)in)[i];
  u16x4 o; o[0] = f2b(v.x); o[1] = f2b(v.y); o[2] = f2b(v.z); o[3] = f2b(v.w);
  ((u16x4*)out)[i] = o;
}

// ---------------------------------------------------------------------------
// W[K][N] fp32 -> WT[N][K] bf16  (tiled 64x64 via LDS)
// ---------------------------------------------------------------------------
__global__ __launch_bounds__(256) void transpose_cvt(
    const float* __restrict__ W, u16* __restrict__ WT, int K, int N) {
  __shared__ float Ts[64][65];
  const int tid = threadIdx.x;
  const int n0 = blockIdx.x * 64, k0 = blockIdx.y * 64;
#pragma unroll
  for (int p = 0; p < 4; ++p) {
    int r = p * 16 + (tid >> 4), c = (tid & 15) * 4;
    float4 v = *(const float4*)(W + (size_t)(k0 + r) * N + n0 + c);
    Ts[r][c] = v.x; Ts[r][c + 1] = v.y; Ts[r][c + 2] = v.z; Ts[r][c + 3] = v.w;
  }
  __syncthreads();
#pragma unroll
  for (int p = 0; p < 4; ++p) {
    int n = p * 16 + (tid >> 4), kq = (tid & 15) * 4;
    u16x4 o;
    o[0] = f2b(Ts[kq + 0][n]); o[1] = f2b(Ts[kq + 1][n]);
    o[2] = f2b(Ts[kq + 2][n]); o[3] = f2b(Ts[kq + 3][n]);
    *(u16x4*)(WT + (size_t)(n0 + n) * K + k0 + kq) = o;
  }
}

// ---------------------------------------------------------------------------
// RoPE in-place on bf16 head-major [BH][S][HD] (K only).
// ---------------------------------------------------------------------------
__global__ __launch_bounds__(256) void rope_bf16(unsigned* __restrict__ T,
                                                 const float* __restrict__ cs,
                                                 const float* __restrict__ sn,
                                                 int total, float scale) {
  int idx = blockIdx.x * 256 + threadIdx.x;
  if (idx >= total) return;
  int i = idx & 63, s = (idx >> 6) & (S_ - 1);
  float c = cs[s * 64 + i], si = sn[s * 64 + i];
  unsigned v = T[idx];
  float re = b2f((u16)(v & 0xffffu)), im = b2f((u16)(v >> 16));
  float ore = (re * c - im * si) * scale, oim = (re * si + im * c) * scale;
  T[idx] = (unsigned)f2b(ore) | ((unsigned)f2b(oim) << 16);
}

// ---------------------------------------------------------------------------
// bf16 MFMA GEMM, m97 structure, XCD-swizzled. KV projection (N=2048):
// heads 0-7 -> K head-major [b,kv,s,d]; heads 8-15 -> V written DIRECTLY
// TRANSPOSED to Vt [b,kv,d,s] (4 s-consecutive values = one 8B store).
// ---------------------------------------------------------------------------
__global__ __launch_bounds__(256) void gemm_kv(
    const u16* __restrict__ A, const u16* __restrict__ Bt,
    u16* __restrict__ Kh, u16* __restrict__ Vt, int M, int N, int K) {
  __shared__ u16 As[128 * 64];
  __shared__ u16 Bs[128 * 64];
  const int tid = threadIdx.x, lane = tid & 63;
  const int wbase = tid & ~63;
  const int o = blockIdx.y * gridDim.x + blockIdx.x;
  const int q8 = (gridDim.x * gridDim.y) >> 3;
  const int p = (o & 7) * q8 + (o >> 3);
  const int row0 = (p / gridDim.x) * 128, col0 = (p % gridDim.x) * 128;
  const int wm = ((tid >> 6) >> 1) * 64, wn = ((tid >> 6) & 1) * 64;

  f32x4 acc[4][4];
#pragma unroll
  for (int i = 0; i < 4; ++i)
#pragma unroll
    for (int j = 0; j < 4; ++j) acc[i][j] = (f32x4){0.f, 0.f, 0.f, 0.f};

  const int nk = K >> 6;
  for (int kt = 0; kt < nk; ++kt) {
    const int k0 = kt << 6;
#pragma unroll
    for (int i = 0; i < 4; ++i) {
      int g = i * 256 + tid;
      int r = g >> 3, ss = (g & 7) ^ (r & 7);
      async_copy16(A + (size_t)(row0 + r) * K + k0 + ss * 8,
                   (char*)As + (i * 256 + wbase) * 16);
    }
#pragma unroll
    for (int i = 0; i < 4; ++i) {
      int g = i * 256 + tid;
      int r = g >> 3, ss = (g & 7) ^ (r & 7);
      async_copy16(Bt + (size_t)(col0 + r) * K + k0 + ss * 8,
                   (char*)Bs + (i * 256 + wbase) * 16);
    }
    __syncthreads();
#pragma unroll
    for (int ks = 0; ks < 2; ++ks) {
      bf16x8 af[4], bf[4];
#pragma unroll
      for (int mi = 0; mi < 4; ++mi) {
        int r = wm + mi * 16 + (lane & 15);
        int off = (ks * 64 + ((lane >> 4) << 4)) ^ ((r & 7) << 4);
        af[mi] = *(const bf16x8*)((const char*)As + r * 128 + off);
      }
#pragma unroll
      for (int ni = 0; ni < 4; ++ni) {
        int r = wn + ni * 16 + (lane & 15);
        int off = (ks * 64 + ((lane >> 4) << 4)) ^ ((r & 7) << 4);
        bf[ni] = *(const bf16x8*)((const char*)Bs + r * 128 + off);
      }
#pragma unroll
      for (int mi = 0; mi < 4; ++mi)
#pragma unroll
        for (int ni = 0; ni < 4; ++ni)
          acc[mi][ni] = __builtin_amdgcn_mfma_f32_16x16x32_bf16(
              af[mi], bf[ni], acc[mi][ni], 0, 0, 0);
    }
    __syncthreads();
  }

#pragma unroll
  for (int mi = 0; mi < 4; ++mi)
#pragma unroll
    for (int ni = 0; ni < 4; ++ni) {
      const int mb = row0 + wm + mi * 16 + ((lane >> 4) << 2);
      const int n = col0 + wn + ni * 16 + (lane & 15);
      const int b = mb >> 11, s0 = mb & (S_ - 1);  // mb%4==0 -> same b for r=0..3
      const int hh = n >> 7, d = n & (HD_ - 1);
      if (hh < 8) {  // K: head-major [b,kv,s,d]
#pragma unroll
        for (int r = 0; r < 4; ++r)
          Kh[(((size_t)(b * 8 + hh)) * S_ + s0 + r) * HD_ + d] =
              f2b(acc[mi][ni][r]);
      } else {  // V: transposed [b,kv,d,s] — 4 consecutive s = 8B store
        u16x4 ov;
#pragma unroll
        for (int r = 0; r < 4; ++r) ov[r] = f2b(acc[mi][ni][r]);
        *(u16x4*)(Vt + (((size_t)(b * 8 + (hh & 7)) * HD_ + d) * S_ + s0)) = ov;
      }
    }
}

// ---------------------------------------------------------------------------
// 256x256 8-phase bf16 MFMA GEMM (R10 schedule — verified; kept frozen).
// ---------------------------------------------------------------------------
template <int OUT_MODE>
__global__ __launch_bounds__(512) void gemm256(
    const u16* __restrict__ A, const u16* __restrict__ Bt,
    void* __restrict__ Cout, int M, int N, int K, int heads) {
  __shared__ u16 lds[65536];  // A: bytes [0,65536), B: [65536,131072)
  char* const ldsb = (char*)lds;
  const int tid = threadIdx.x, lane = tid & 63, wid = tid >> 6;
  const int q = lane & 15, g = lane >> 4;
  const int wm = wid >> 2, wn = wid & 3;
  const int o = blockIdx.y * gridDim.x + blockIdx.x;
  const int q8 = (gridDim.x * gridDim.y) >> 3;
  const int p = (o & 7) * q8 + (o >> 3);
  const int row0 = (p / gridDim.x) * 256, col0 = (p % gridDim.x) * 256;
  const int nk = K >> 6, nh = nk << 2;

  const u16* srcA[2];
  const u16* srcB[2];
#pragma unroll
  for (int u = 0; u < 2; ++u) {
    int j = u * 512 + tid;
    int row = ((j >> 3) << 1) + ((j >> 2) & 1);
    int colg = (j & 3) ^ ((j >> 3) & 3);
    srcA[u] = A + (size_t)(row0 + row) * K + colg * 8;
    srcB[u] = Bt + (size_t)(col0 + row) * K + colg * 8;
  }

  auto STAGE = [&](int h) {
    if (h >= nh) return;
    int tau = h >> 2, ks = (h >> 1) & 1, op = h & 1;
    int slot = (2 * tau + ks) & 3;
    int koff = tau * 64 + ks * 32;
    char* lbase = ldsb + op * 65536 + slot * 16384 + wid * 1024;
#pragma unroll
    for (int u = 0; u < 2; ++u)
      async_copy16((op ? srcB[u] : srcA[u]) + koff, lbase + u * 8192);
  };

  int aread[8], bread[4];
#pragma unroll
  for (int mi = 0; mi < 8; ++mi) {
    int row = wm * 128 + mi * 16 + q;
    aread[mi] = (row >> 1) * 128 + (row & 1) * 64 + ((g ^ ((row >> 1) & 3)) << 4);
  }
#pragma unroll
  for (int ni = 0; ni < 4; ++ni) {
    int row = wn * 64 + ni * 16 + q;
    bread[ni] = (row >> 1) * 128 + (row & 1) * 64 + ((g ^ ((row >> 1) & 3)) << 4);
  }

  f32x4 acc[8][4];
#pragma unroll
  for (int i = 0; i < 8; ++i)
#pragma unroll
    for (int j = 0; j < 4; ++j) acc[i][j] = (f32x4){0.f, 0.f, 0.f, 0.f};

  auto RDA = [&](bf16x8* d, const char* s, int ob) {
#pragma unroll
    for (int i = 0; i < 4; ++i) d[i] = *(const bf16x8*)(s + aread[ob + i]);
  };
  auto RDB = [&](bf16x8* d, const char* s) {
#pragma unroll
    for (int i = 0; i < 4; ++i) d[i] = *(const bf16x8*)(s + bread[i]);
  };
  auto MFMA16 = [&](int mo, bf16x8* af, bf16x8* bfr) {
    __builtin_amdgcn_s_setprio(1);
#pragma unroll
    for (int mi = 0; mi < 4; ++mi)
#pragma unroll
      for (int ni = 0; ni < 4; ++ni)
        acc[mo + mi][ni] = __builtin_amdgcn_mfma_f32_16x16x32_bf16(
            af[mi], bfr[ni], acc[mo + mi][ni], 0, 0, 0);
    __builtin_amdgcn_s_setprio(0);
  };

#pragma unroll
  for (int h = 0; h < 6; ++h) STAGE(h);
  asm volatile("s_waitcnt vmcnt(4)" ::: "memory");
  bar();
  bf16x8 afc[4], afn[4], bfc[4], bfn[4];
  RDA(afc, ldsb, 0);
  RDB(bfc, ldsb + 65536);

  for (int t = 0; t < nk; ++t) {
    const int s0 = (2 * t) & 3, s1 = (2 * t + 1) & 3;
    const char* As0 = ldsb + s0 * 16384;
    const char* Bs1 = ldsb + 65536 + s1 * 16384;
    const char* As1 = ldsb + s1 * 16384;

    STAGE(4 * t + 6);
    bar();
    MFMA16(0, afc, bfc);
    RDA(afn, As0, 4);
    bar();

    STAGE(4 * t + 7);
    bar();
    MFMA16(4, afn, bfc);
    RDA(afc, As1, 0);
    RDB(bfn, Bs1);
    bar();

    STAGE(4 * t + 8);
    bar();
    MFMA16(0, afc, bfn);
    RDA(afn, As1, 4);
    bar();

    STAGE(4 * t + 9);
    bar();
    MFMA16(4, afn, bfn);
    if (t < nk - 2)
      asm volatile("s_waitcnt vmcnt(4)" ::: "memory");
    else if (t == nk - 2)
      asm volatile("s_waitcnt vmcnt(0)" ::: "memory");
    if (t < nk - 1) {
      const char* As0n = ldsb + ((2 * t + 2) & 3) * 16384;
      const char* Bs0n = ldsb + 65536 + ((2 * t + 2) & 3) * 16384;
      RDA(afc, As0n, 0);
      RDB(bfc, Bs0n);
    }
    bar();
  }

#pragma unroll
  for (int mi = 0; mi < 8; ++mi)
#pragma unroll
    for (int ni = 0; ni < 4; ++ni) {
      int mb = row0 + wm * 128 + mi * 16 + (g << 2);
      int n = col0 + wn * 64 + ni * 16 + q;
#pragma unroll
      for (int r = 0; r < 4; ++r) {
        int m = mb + r;
        float v = acc[mi][ni][r];
        if (OUT_MODE == 0) {
          ((float*)Cout)[(size_t)m * N + n] = v;
        } else {
          int b = m >> 11, s = m & (S_ - 1);
          int h = n >> 7, d = n & (HD_ - 1);
          ((u16*)Cout)[(((size_t)(b * heads + h)) * S_ + s) * HD_ + d] = f2b(v);
        }
      }
    }
}

// ---------------------------------------------------------------------------
// Flash attention, 32x32x16 MFMA + dbuf K/V prefetch (R10 structure) +
// s_setprio around MFMA clusters (T5) + 4-way-ILP softmax reductions.
// ---------------------------------------------------------------------------
__global__ __launch_bounds__(256, 2) void attn_mfma(
    const u16* __restrict__ Qb, const u16* __restrict__ Kb,
    const u16* __restrict__ Vt, u16* __restrict__ AO,
    const float* __restrict__ fc, const float* __restrict__ fs) {
  __shared__ u16 Ks[2][64 * 128];  // [kv][d] 256B rows, swizzled
  __shared__ u16 Vs[2][128 * 64];  // [d][kv] 128B rows, swizzled

  const int tid = threadIdx.x, lane = tid & 63, wid = tid >> 6;
  const int wbase = tid & ~63;
  const int o = blockIdx.x + (blockIdx.y << 3) + (blockIdx.z << 8);
  const int pid = o >> 6, h = o & 31, b = (o >> 5) & 1;
  const int kvh = h >> 2;
  const int l31 = lane & 31, hi = lane >> 5;

  const u16* Kbase = Kb + ((size_t)(b * KV_ + kvh) * S_) * HD_;
  const u16* Vbase = Vt + ((size_t)(b * KV_ + kvh) * HD_) * S_;

  const u16* Kl[4];
  const u16* Vl[4];
#pragma unroll
  for (int i = 0; i < 4; ++i) {
    int gg = i * 256 + tid;
    int rK = gg >> 4, ssK = (gg & 15) ^ (rK & 7);
    Kl[i] = Kbase + (size_t)rK * HD_ + ssK * 8;
    int rV = gg >> 3, ssV = (gg & 7) ^ (rV & 7);
    Vl[i] = Vbase + (size_t)rV * S_ + ssV * 8;
  }

  auto STAGE_KV = [&](int kt, int buf) {
    const int kv0 = kt * 64;
#pragma unroll
    for (int i = 0; i < 4; ++i)
      async_copy16(Kl[i] + (size_t)kv0 * HD_,
                   (char*)Ks[buf] + (i * 256 + wbase) * 16);
#pragma unroll
    for (int i = 0; i < 4; ++i)
      async_copy16(Vl[i] + kv0, (char*)Vs[buf] + (i * 256 + wbase) * 16);
  };

  for (int half = 0; half < 2; ++half) {
    const int qt = half ? (15 - pid) : pid;
    const int q0 = qt * 128;
    const int qg = q0 + wid * 32 + l31;  // this lane's q-row

    STAGE_KV(0, 0);

    // ---- Q load + fused RoPE + QSCALE (overlaps tile-0 staging)
    bf16x8 qf[8];
    {
      const u16* qrow = Qb + ((size_t)(b * H_ + h) * S_ + qg) * HD_ + hi * 8;
      const float* cb = fc + qg * 64 + hi * 4;
      const float* sb = fs + qg * 64 + hi * 4;
#pragma unroll
      for (int ks = 0; ks < 8; ++ks) {
        u16x8 v = *(const u16x8*)(qrow + ks * 16);
        float4 cv = *(const float4*)(cb + ks * 8);
        float4 sv = *(const float4*)(sb + ks * 8);
        unsigned w[4];
#pragma unroll
        for (int j = 0; j < 4; ++j) {
          float c = ((const float*)&cv)[j] * QSCALE_;
          float s = ((const float*)&sv)[j] * QSCALE_;
          float re = b2f((u16)v[2 * j]), im = b2f((u16)v[2 * j + 1]);
          w[j] = cvt_pk_bf16(re * c - im * s, re * s + im * c);
        }
        union { unsigned u[4]; bf16x8 q; } cvt;
        cvt.u[0] = w[0]; cvt.u[1] = w[1]; cvt.u[2] = w[2]; cvt.u[3] = w[3];
        qf[ks] = cvt.q;
      }
    }

    f32x16 oacc[4];
#pragma unroll
    for (int i = 0; i < 4; ++i)
#pragma unroll
      for (int j = 0; j < 16; ++j) oacc[i][j] = 0.f;
    float mrow = -3e38f, lrow = 0.f;

    __syncthreads();  // tile 0 landed + all waves ready

    const int nkt = 2 * qt + 2;
    for (int kt = 0; kt < nkt; ++kt) {
      const int cur = kt & 1;
      if (kt + 1 < nkt) STAGE_KV(kt + 1, cur ^ 1);  // prefetch next tile
      const char* Kc = (const char*)Ks[cur];
      const char* Vc = (const char*)Vs[cur];
      const int kv0 = kt * 64;

      // ---- S^T = K Q^T  (2 kv-frags x 8 d-steps)
      f32x16 sacc[2];
#pragma unroll
      for (int kf = 0; kf < 2; ++kf)
#pragma unroll
        for (int j = 0; j < 16; ++j) sacc[kf][j] = 0.f;
      __builtin_amdgcn_s_setprio(1);
#pragma unroll
      for (int ks = 0; ks < 8; ++ks) {
#pragma unroll
        for (int kf = 0; kf < 2; ++kf) {
          const int arow = kf * 32 + l31;
          bf16x8 kfrag = *(const bf16x8*)(
              Kc + arow * 256 + ((((ks * 2 + hi) << 4)) ^ ((arow & 7) << 4)));
          sacc[kf] = __builtin_amdgcn_mfma_f32_32x32x16_bf16(kfrag, qf[ks],
                                                             sacc[kf], 0, 0, 0);
        }
      }
      __builtin_amdgcn_s_setprio(0);

      // ---- causal mask (elementwise; wave-uniform condition)
      if (kv0 + 63 > q0 + wid * 32) {
#pragma unroll
        for (int kf = 0; kf < 2; ++kf)
#pragma unroll
          for (int r = 0; r < 16; ++r) {
            int kg = kv0 + kf * 32 + (r & 3) + 8 * (r >> 2) + 4 * hi;
            if (kg > qg) sacc[kf][r] = -3e38f;
          }
      }

      // ---- in-register online softmax (log2 domain), 4-way-ILP reductions
      float m0 = -3e38f, m1 = -3e38f, m2 = -3e38f, m3 = -3e38f;
#pragma unroll
      for (int kf = 0; kf < 2; ++kf)
#pragma unroll
        for (int r = 0; r < 4; ++r) {
          m0 = fmaxf(m0, sacc[kf][r]);
          m1 = fmaxf(m1, sacc[kf][r + 4]);
          m2 = fmaxf(m2, sacc[kf][r + 8]);
          m3 = fmaxf(m3, sacc[kf][r + 12]);
        }
      float rmax = fmaxf(fmaxf(m0, m1), fmaxf(m2, m3));
      rmax = fmaxf(rmax, __shfl_xor(rmax, 32, 64));
      const bool defer = __all(rmax - mrow <= 11.5f);
      float mnew, fsc;
      if (defer) {
        mnew = mrow; fsc = 1.0f;
      } else {
        mnew = fmaxf(mrow, rmax); fsc = exp2f(mrow - mnew);
      }
      mrow = mnew;
      float p0 = 0.f, p1 = 0.f, p2 = 0.f, p3 = 0.f;
#pragma unroll
      for (int kf = 0; kf < 2; ++kf)
#pragma unroll
        for (int r = 0; r < 4; ++r) {
          float e0 = exp2f(sacc[kf][r] - mnew);
          float e1 = exp2f(sacc[kf][r + 4] - mnew);
          float e2 = exp2f(sacc[kf][r + 8] - mnew);
          float e3 = exp2f(sacc[kf][r + 12] - mnew);
          sacc[kf][r] = e0; sacc[kf][r + 4] = e1;
          sacc[kf][r + 8] = e2; sacc[kf][r + 12] = e3;
          p0 += e0; p1 += e1; p2 += e2; p3 += e3;
        }
      float psum = (p0 + p1) + (p2 + p3);
      psum += __shfl_xor(psum, 32, 64);
      lrow = lrow * fsc + psum;

      if (!defer) {  // rare: redistribute fsc to O rows (q' = crow(r,hi))
#pragma unroll
        for (int r = 0; r < 16; ++r) {
          float fr = __shfl(fsc, (r & 3) + 8 * (r >> 2) + 4 * hi, 64);
#pragma unroll
          for (int df = 0; df < 4; ++df) oacc[df][r] *= fr;
        }
      }

      // ---- P -> registers: cvt_pk pairs + permlane32_swap -> A-frags
      bf16x8 pa[4];
#pragma unroll
      for (int kf = 0; kf < 2; ++kf) {
        unsigned w0 = cvt_pk_bf16(sacc[kf][0], sacc[kf][1]);
        unsigned w1 = cvt_pk_bf16(sacc[kf][2], sacc[kf][3]);
        unsigned w2 = cvt_pk_bf16(sacc[kf][4], sacc[kf][5]);
        unsigned w3 = cvt_pk_bf16(sacc[kf][6], sacc[kf][7]);
        unsigned w4 = cvt_pk_bf16(sacc[kf][8], sacc[kf][9]);
        unsigned w5 = cvt_pk_bf16(sacc[kf][10], sacc[kf][11]);
        unsigned w6 = cvt_pk_bf16(sacc[kf][12], sacc[kf][13]);
        unsigned w7 = cvt_pk_bf16(sacc[kf][14], sacc[kf][15]);
        asm volatile("v_permlane32_swap_b32 %0, %1" : "+v"(w0), "+v"(w2));
        asm volatile("v_permlane32_swap_b32 %0, %1" : "+v"(w1), "+v"(w3));
        asm volatile("v_permlane32_swap_b32 %0, %1" : "+v"(w4), "+v"(w6));
        asm volatile("v_permlane32_swap_b32 %0, %1" : "+v"(w5), "+v"(w7));
        union { unsigned u[4]; bf16x8 q; } f0, f1;
        f0.u[0] = w0; f0.u[1] = w1; f0.u[2] = w2; f0.u[3] = w3;
        f1.u[0] = w4; f1.u[1] = w5; f1.u[2] = w6; f1.u[3] = w7;
        pa[kf * 2] = f0.q;
        pa[kf * 2 + 1] = f1.q;
      }

      // ---- O += P @ V  (4 d-frags x 4 kv-steps)
      __builtin_amdgcn_s_setprio(1);
#pragma unroll
      for (int ks = 0; ks < 4; ++ks) {
#pragma unroll
        for (int df = 0; df < 4; ++df) {
          const int vrow = df * 32 + l31;
          bf16x8 vf = *(const bf16x8*)(
              Vc + vrow * 128 + ((((ks * 2 + hi) << 4)) ^ ((vrow & 7) << 4)));
          oacc[df] = __builtin_amdgcn_mfma_f32_32x32x16_bf16(pa[ks], vf,
                                                             oacc[df], 0, 0, 0);
        }
      }
      __builtin_amdgcn_s_setprio(0);
      __syncthreads();  // drains prefetch (overlapped by this tile's compute)
    }

    // ---- epilogue: O[q'][d = df*32+l31]
    const float linv = 1.f / lrow;
#pragma unroll
    for (int r = 0; r < 16; ++r) {
      const int qloc = (r & 3) + 8 * (r >> 2) + 4 * hi;
      const float invq = __shfl(linv, qloc, 64);
      const int sq = q0 + wid * 32 + qloc;
      u16* dst = AO + (size_t)(b * S_ + sq) * (H_ * HD_) + h * HD_ + l31;
#pragma unroll
      for (int df = 0; df < 4; ++df) dst[df * 32] = f2b(oacc[df][r] * invq);
    }
  }
}

// ---------------------------------------------------------------------------
extern "C" void kernel_launch(void* const* d_in, const int* in_sizes, int n_in,
                              void* d_out, int out_size, void* d_ws, size_t ws_size,
                              hipStream_t stream) {
  const float* x  = (const float*)d_in[0];
  const float* wq = (const float*)d_in[1];
  const float* wk = (const float*)d_in[2];
  const float* wv = (const float*)d_in[3];
  const float* wo = (const float*)d_in[4];
  const float* fc = (const float*)d_in[5];
  const float* fs = (const float*)d_in[6];
  float* out = (float*)d_out;

  // Workspace (u16 elements), 160 MiB total — same layout as R3-R10.
  // V is now written directly transposed into VtB by gemm_kv (Vh unused).
  u16* ws  = (u16*)d_ws;
  u16* wqT = ws;
  u16* VtB = ws;              // alias of wqT region (written after Q-proj reads wqT)
  u16* xb  = ws + 16777216;
  u16* AOb = xb;              // alias of xb region (after xb last use)
  u16* woT = ws + 33554432;
  u16* Qh  = ws + 50331648;
  u16* wkT = ws + 67108864;
  u16* wvT = ws + 71303168;
  u16* Kh  = ws + 75497472;

  dim3 blk(256);

  cvt_bf16<<<dim3(16384), blk, 0, stream>>>(x, xb, 4194304);
  transpose_cvt<<<dim3(64, 64), blk, 0, stream>>>(wq, wqT, DIM_, H_ * HD_);
  transpose_cvt<<<dim3(16, 64), blk, 0, stream>>>(wk, wkT, DIM_, KV_ * HD_);
  transpose_cvt<<<dim3(16, 64), blk, 0, stream>>>(wv, wvT, DIM_, KV_ * HD_);
  transpose_cvt<<<dim3(64, 64), blk, 0, stream>>>(wo, woT, H_ * HD_, DIM_);

  gemm256<1><<<dim3(16, 16), dim3(512), 0, stream>>>(xb, wqT, Qh, 4096, 4096, 4096, H_);
  // combined K+V projection; K -> Kh head-major, V -> VtB transposed
  gemm_kv<<<dim3(16, 32), blk, 0, stream>>>(xb, wkT, Kh, VtB, 4096, 2048, 4096);

  rope_bf16<<<dim3(8192), blk, 0, stream>>>((unsigned*)Kh, fc, fs, 2097152, 1.0f);

  attn_mfma<<<dim3(8, 32, 2), blk, 0, stream>>>(Qh, Kh, VtB, AOb, fc, fs);

  gemm256<0><<<dim3(16, 16), dim3(512), 0, stream>>>(AOb, woT, out, 4096, 4096, 4096, 0);
}

// Round 12
// 508.490 us; speedup vs baseline: 1.0272x; 1.0272x over previous
//
#include <hip/hip_runtime.h>
#include <math.h>

#define B_ 2
#define S_ 2048
#define DIM_ 4096
#define H_ 32
#define KV_ 8
#define HD_ 128
#define SCALE_ 0.08838834764831844f   // 128^-0.5
#define QSCALE_ 0.12751744154254998f  // SCALE_ * log2(e)

typedef unsigned short u16;
typedef __attribute__((ext_vector_type(8))) short bf16x8;
typedef __attribute__((ext_vector_type(4))) float f32x4;
typedef __attribute__((ext_vector_type(16))) float f32x16;
typedef __attribute__((ext_vector_type(8))) unsigned short u16x8;
typedef __attribute__((ext_vector_type(4))) unsigned short u16x4;

__device__ __forceinline__ u16 f2b(float f) {  // RNE f32->bf16
  union { float f; unsigned u; } v; v.f = f;
  unsigned r = v.u + 0x7fffu + ((v.u >> 16) & 1u);
  return (u16)(r >> 16);
}
__device__ __forceinline__ float b2f(u16 h) {
  union { unsigned u; float f; } v; v.u = ((unsigned)h) << 16;
  return v.f;
}
// HW packed f32->bf16 (RNE): lo -> bits[15:0], hi -> bits[31:16]
__device__ __forceinline__ unsigned cvt_pk_bf16(float lo, float hi) {
  unsigned r;
  asm("v_cvt_pk_bf16_f32 %0, %1, %2" : "=v"(r) : "v"(lo), "v"(hi));
  return r;
}
// Direct-to-LDS async copy, 16B/lane. LDS dest = wave-uniform base + lane*16.
__device__ __forceinline__ void async_copy16(const void* g, void* l) {
  __builtin_amdgcn_global_load_lds(
      (const __attribute__((address_space(1))) void*)g,
      (__attribute__((address_space(3))) void*)l, 16, 0, 0);
}
// Raw barrier WITH compiler memory fence (no vmcnt drain, unlike __syncthreads)
__device__ __forceinline__ void bar() {
  asm volatile("s_barrier" ::: "memory");
}

// ---------------------------------------------------------------------------
// Fused prep: ONE launch for {x->bf16 cvt, wq/wk/wv/wo transpose+cvt}.
// Block ranges: [0,16384) cvt; [16384,20480) wq; [20480,21504) wk;
// [21504,22528) wv; [22528,26624) wo.  All 5 are mutually independent.
// ---------------------------------------------------------------------------
__global__ __launch_bounds__(256) void prep_fused(
    const float* __restrict__ x, u16* __restrict__ xb,
    const float* __restrict__ wq, u16* __restrict__ wqT,
    const float* __restrict__ wk, u16* __restrict__ wkT,
    const float* __restrict__ wv, u16* __restrict__ wvT,
    const float* __restrict__ wo, u16* __restrict__ woT) {
  __shared__ float Ts[64][65];
  const int tid = threadIdx.x;
  const int bid = blockIdx.x;

  if (bid < 16384) {  // ---- bulk cvt: x (fp32) -> xb (bf16), float4/thread
    int i = bid * 256 + tid;
    float4 v = ((const float4*)x)[i];
    u16x4 o; o[0] = f2b(v.x); o[1] = f2b(v.y); o[2] = f2b(v.z); o[3] = f2b(v.w);
    ((u16x4*)xb)[i] = o;
    return;
  }

  // ---- transpose_cvt: W[K][N] fp32 -> WT[N][K] bf16, 64x64 tile
  const float* W; u16* WT; int K, N, gx, v;
  if (bid < 20480)      { W = wq; WT = wqT; K = DIM_; N = H_ * HD_;  gx = 64; v = bid - 16384; }
  else if (bid < 21504) { W = wk; WT = wkT; K = DIM_; N = KV_ * HD_; gx = 16; v = bid - 20480; }
  else if (bid < 22528) { W = wv; WT = wvT; K = DIM_; N = KV_ * HD_; gx = 16; v = bid - 21504; }
  else                  { W = wo; WT = woT; K = H_ * HD_; N = DIM_;  gx = 64; v = bid - 22528; }
  const int n0 = (v % gx) * 64, k0 = (v / gx) * 64;

#pragma unroll
  for (int p = 0; p < 4; ++p) {
    int r = p * 16 + (tid >> 4), c = (tid & 15) * 4;
    float4 w = *(const float4*)(W + (size_t)(k0 + r) * N + n0 + c);
    Ts[r][c] = w.x; Ts[r][c + 1] = w.y; Ts[r][c + 2] = w.z; Ts[r][c + 3] = w.w;
  }
  __syncthreads();
#pragma unroll
  for (int p = 0; p < 4; ++p) {
    int n = p * 16 + (tid >> 4), kq = (tid & 15) * 4;
    u16x4 o;
    o[0] = f2b(Ts[kq + 0][n]); o[1] = f2b(Ts[kq + 1][n]);
    o[2] = f2b(Ts[kq + 2][n]); o[3] = f2b(Ts[kq + 3][n]);
    *(u16x4*)(WT + (size_t)(n0 + n) * K + k0 + kq) = o;
  }
}

// ---------------------------------------------------------------------------
// RoPE in-place on bf16 head-major [BH][S][HD] (K only).
// ---------------------------------------------------------------------------
__global__ __launch_bounds__(256) void rope_bf16(unsigned* __restrict__ T,
                                                 const float* __restrict__ cs,
                                                 const float* __restrict__ sn,
                                                 int total, float scale) {
  int idx = blockIdx.x * 256 + threadIdx.x;
  if (idx >= total) return;
  int i = idx & 63, s = (idx >> 6) & (S_ - 1);
  float c = cs[s * 64 + i], si = sn[s * 64 + i];
  unsigned v = T[idx];
  float re = b2f((u16)(v & 0xffffu)), im = b2f((u16)(v >> 16));
  float ore = (re * c - im * si) * scale, oim = (re * si + im * c) * scale;
  T[idx] = (unsigned)f2b(ore) | ((unsigned)f2b(oim) << 16);
}

// ---------------------------------------------------------------------------
// bf16 MFMA GEMM, m97 structure, XCD-swizzled. KV projection (N=2048):
// heads 0-7 -> K head-major [b,kv,s,d]; heads 8-15 -> V written DIRECTLY
// TRANSPOSED to Vt [b,kv,d,s] (4 s-consecutive values = one 8B store).
// ---------------------------------------------------------------------------
__global__ __launch_bounds__(256) void gemm_kv(
    const u16* __restrict__ A, const u16* __restrict__ Bt,
    u16* __restrict__ Kh, u16* __restrict__ Vt, int M, int N, int K) {
  __shared__ u16 As[128 * 64];
  __shared__ u16 Bs[128 * 64];
  const int tid = threadIdx.x, lane = tid & 63;
  const int wbase = tid & ~63;
  const int o = blockIdx.y * gridDim.x + blockIdx.x;
  const int q8 = (gridDim.x * gridDim.y) >> 3;
  const int p = (o & 7) * q8 + (o >> 3);
  const int row0 = (p / gridDim.x) * 128, col0 = (p % gridDim.x) * 128;
  const int wm = ((tid >> 6) >> 1) * 64, wn = ((tid >> 6) & 1) * 64;

  f32x4 acc[4][4];
#pragma unroll
  for (int i = 0; i < 4; ++i)
#pragma unroll
    for (int j = 0; j < 4; ++j) acc[i][j] = (f32x4){0.f, 0.f, 0.f, 0.f};

  const int nk = K >> 6;
  for (int kt = 0; kt < nk; ++kt) {
    const int k0 = kt << 6;
#pragma unroll
    for (int i = 0; i < 4; ++i) {
      int g = i * 256 + tid;
      int r = g >> 3, ss = (g & 7) ^ (r & 7);
      async_copy16(A + (size_t)(row0 + r) * K + k0 + ss * 8,
                   (char*)As + (i * 256 + wbase) * 16);
    }
#pragma unroll
    for (int i = 0; i < 4; ++i) {
      int g = i * 256 + tid;
      int r = g >> 3, ss = (g & 7) ^ (r & 7);
      async_copy16(Bt + (size_t)(col0 + r) * K + k0 + ss * 8,
                   (char*)Bs + (i * 256 + wbase) * 16);
    }
    __syncthreads();
#pragma unroll
    for (int ks = 0; ks < 2; ++ks) {
      bf16x8 af[4], bf[4];
#pragma unroll
      for (int mi = 0; mi < 4; ++mi) {
        int r = wm + mi * 16 + (lane & 15);
        int off = (ks * 64 + ((lane >> 4) << 4)) ^ ((r & 7) << 4);
        af[mi] = *(const bf16x8*)((const char*)As + r * 128 + off);
      }
#pragma unroll
      for (int ni = 0; ni < 4; ++ni) {
        int r = wn + ni * 16 + (lane & 15);
        int off = (ks * 64 + ((lane >> 4) << 4)) ^ ((r & 7) << 4);
        bf[ni] = *(const bf16x8*)((const char*)Bs + r * 128 + off);
      }
#pragma unroll
      for (int mi = 0; mi < 4; ++mi)
#pragma unroll
        for (int ni = 0; ni < 4; ++ni)
          acc[mi][ni] = __builtin_amdgcn_mfma_f32_16x16x32_bf16(
              af[mi], bf[ni], acc[mi][ni], 0, 0, 0);
    }
    __syncthreads();
  }

#pragma unroll
  for (int mi = 0; mi < 4; ++mi)
#pragma unroll
    for (int ni = 0; ni < 4; ++ni) {
      const int mb = row0 + wm + mi * 16 + ((lane >> 4) << 2);
      const int n = col0 + wn + ni * 16 + (lane & 15);
      const int b = mb >> 11, s0 = mb & (S_ - 1);  // mb%4==0 -> same b for r=0..3
      const int hh = n >> 7, d = n & (HD_ - 1);
      if (hh < 8) {  // K: head-major [b,kv,s,d]
#pragma unroll
        for (int r = 0; r < 4; ++r)
          Kh[(((size_t)(b * 8 + hh)) * S_ + s0 + r) * HD_ + d] =
              f2b(acc[mi][ni][r]);
      } else {  // V: transposed [b,kv,d,s] — 4 consecutive s = 8B store
        u16x4 ov;
#pragma unroll
        for (int r = 0; r < 4; ++r) ov[r] = f2b(acc[mi][ni][r]);
        *(u16x4*)(Vt + (((size_t)(b * 8 + (hh & 7)) * HD_ + d) * S_ + s0)) = ov;
      }
    }
}

// ---------------------------------------------------------------------------
// 256x256 8-phase bf16 MFMA GEMM (R10 schedule) + constexpr NK=64 and
// 2-K-tile unroll (m201 iteration granularity; folds ring-slot arithmetic).
// ---------------------------------------------------------------------------
template <int OUT_MODE>
__global__ __launch_bounds__(512) void gemm256(
    const u16* __restrict__ A, const u16* __restrict__ Bt,
    void* __restrict__ Cout, int M, int N, int heads) {
  constexpr int K = 4096;
  constexpr int nk = K >> 6;
  constexpr int nh = nk << 2;
  __shared__ u16 lds[65536];  // A: bytes [0,65536), B: [65536,131072)
  char* const ldsb = (char*)lds;
  const int tid = threadIdx.x, lane = tid & 63, wid = tid >> 6;
  const int q = lane & 15, g = lane >> 4;
  const int wm = wid >> 2, wn = wid & 3;
  const int o = blockIdx.y * gridDim.x + blockIdx.x;
  const int q8 = (gridDim.x * gridDim.y) >> 3;
  const int p = (o & 7) * q8 + (o >> 3);
  const int row0 = (p / gridDim.x) * 256, col0 = (p % gridDim.x) * 256;

  const u16* srcA[2];
  const u16* srcB[2];
#pragma unroll
  for (int u = 0; u < 2; ++u) {
    int j = u * 512 + tid;
    int row = ((j >> 3) << 1) + ((j >> 2) & 1);
    int colg = (j & 3) ^ ((j >> 3) & 3);
    srcA[u] = A + (size_t)(row0 + row) * K + colg * 8;
    srcB[u] = Bt + (size_t)(col0 + row) * K + colg * 8;
  }

  auto STAGE = [&](int h) {
    if (h >= nh) return;
    int tau = h >> 2, ks = (h >> 1) & 1, op = h & 1;
    int slot = (2 * tau + ks) & 3;
    int koff = tau * 64 + ks * 32;
    char* lbase = ldsb + op * 65536 + slot * 16384 + wid * 1024;
#pragma unroll
    for (int u = 0; u < 2; ++u)
      async_copy16((op ? srcB[u] : srcA[u]) + koff, lbase + u * 8192);
  };

  int aread[8], bread[4];
#pragma unroll
  for (int mi = 0; mi < 8; ++mi) {
    int row = wm * 128 + mi * 16 + q;
    aread[mi] = (row >> 1) * 128 + (row & 1) * 64 + ((g ^ ((row >> 1) & 3)) << 4);
  }
#pragma unroll
  for (int ni = 0; ni < 4; ++ni) {
    int row = wn * 64 + ni * 16 + q;
    bread[ni] = (row >> 1) * 128 + (row & 1) * 64 + ((g ^ ((row >> 1) & 3)) << 4);
  }

  f32x4 acc[8][4];
#pragma unroll
  for (int i = 0; i < 8; ++i)
#pragma unroll
    for (int j = 0; j < 4; ++j) acc[i][j] = (f32x4){0.f, 0.f, 0.f, 0.f};

  auto RDA = [&](bf16x8* d, const char* s, int ob) {
#pragma unroll
    for (int i = 0; i < 4; ++i) d[i] = *(const bf16x8*)(s + aread[ob + i]);
  };
  auto RDB = [&](bf16x8* d, const char* s) {
#pragma unroll
    for (int i = 0; i < 4; ++i) d[i] = *(const bf16x8*)(s + bread[i]);
  };
  auto MFMA16 = [&](int mo, bf16x8* af, bf16x8* bfr) {
    __builtin_amdgcn_s_setprio(1);
#pragma unroll
    for (int mi = 0; mi < 4; ++mi)
#pragma unroll
      for (int ni = 0; ni < 4; ++ni)
        acc[mo + mi][ni] = __builtin_amdgcn_mfma_f32_16x16x32_bf16(
            af[mi], bfr[ni], acc[mo + mi][ni], 0, 0, 0);
    __builtin_amdgcn_s_setprio(0);
  };

#pragma unroll
  for (int h = 0; h < 6; ++h) STAGE(h);
  asm volatile("s_waitcnt vmcnt(4)" ::: "memory");
  bar();
  bf16x8 afc[4], afn[4], bfc[4], bfn[4];
  RDA(afc, ldsb, 0);
  RDB(bfc, ldsb + 65536);

#pragma unroll 2
  for (int t = 0; t < nk; ++t) {
    const int s0 = (2 * t) & 3, s1 = (2 * t + 1) & 3;
    const char* As0 = ldsb + s0 * 16384;
    const char* Bs1 = ldsb + 65536 + s1 * 16384;
    const char* As1 = ldsb + s1 * 16384;

    STAGE(4 * t + 6);
    bar();
    MFMA16(0, afc, bfc);
    RDA(afn, As0, 4);
    bar();

    STAGE(4 * t + 7);
    bar();
    MFMA16(4, afn, bfc);
    RDA(afc, As1, 0);
    RDB(bfn, Bs1);
    bar();

    STAGE(4 * t + 8);
    bar();
    MFMA16(0, afc, bfn);
    RDA(afn, As1, 4);
    bar();

    STAGE(4 * t + 9);
    bar();
    MFMA16(4, afn, bfn);
    if (t < nk - 2)
      asm volatile("s_waitcnt vmcnt(4)" ::: "memory");
    else if (t == nk - 2)
      asm volatile("s_waitcnt vmcnt(0)" ::: "memory");
    if (t < nk - 1) {
      const char* As0n = ldsb + ((2 * t + 2) & 3) * 16384;
      const char* Bs0n = ldsb + 65536 + ((2 * t + 2) & 3) * 16384;
      RDA(afc, As0n, 0);
      RDB(bfc, Bs0n);
    }
    bar();
  }

#pragma unroll
  for (int mi = 0; mi < 8; ++mi)
#pragma unroll
    for (int ni = 0; ni < 4; ++ni) {
      int mb = row0 + wm * 128 + mi * 16 + (g << 2);
      int n = col0 + wn * 64 + ni * 16 + q;
#pragma unroll
      for (int r = 0; r < 4; ++r) {
        int m = mb + r;
        float v = acc[mi][ni][r];
        if (OUT_MODE == 0) {
          ((float*)Cout)[(size_t)m * N + n] = v;
        } else {
          int b = m >> 11, s = m & (S_ - 1);
          int h = n >> 7, d = n & (HD_ - 1);
          ((u16*)Cout)[(((size_t)(b * heads + h)) * S_ + s) * HD_ + d] = f2b(v);
        }
      }
    }
}

// ---------------------------------------------------------------------------
// Flash attention, 32x32x16 MFMA + dbuf K/V prefetch + 4-way-ILP softmax.
// (setprio REMOVED: 4-wave lockstep blocks = m190 regime where it hurts.)
// ---------------------------------------------------------------------------
__global__ __launch_bounds__(256, 2) void attn_mfma(
    const u16* __restrict__ Qb, const u16* __restrict__ Kb,
    const u16* __restrict__ Vt, u16* __restrict__ AO,
    const float* __restrict__ fc, const float* __restrict__ fs) {
  __shared__ u16 Ks[2][64 * 128];  // [kv][d] 256B rows, swizzled
  __shared__ u16 Vs[2][128 * 64];  // [d][kv] 128B rows, swizzled

  const int tid = threadIdx.x, lane = tid & 63, wid = tid >> 6;
  const int wbase = tid & ~63;
  const int o = blockIdx.x + (blockIdx.y << 3) + (blockIdx.z << 8);
  const int pid = o >> 6, h = o & 31, b = (o >> 5) & 1;
  const int kvh = h >> 2;
  const int l31 = lane & 31, hi = lane >> 5;

  const u16* Kbase = Kb + ((size_t)(b * KV_ + kvh) * S_) * HD_;
  const u16* Vbase = Vt + ((size_t)(b * KV_ + kvh) * HD_) * S_;

  const u16* Kl[4];
  const u16* Vl[4];
#pragma unroll
  for (int i = 0; i < 4; ++i) {
    int gg = i * 256 + tid;
    int rK = gg >> 4, ssK = (gg & 15) ^ (rK & 7);
    Kl[i] = Kbase + (size_t)rK * HD_ + ssK * 8;
    int rV = gg >> 3, ssV = (gg & 7) ^ (rV & 7);
    Vl[i] = Vbase + (size_t)rV * S_ + ssV * 8;
  }

  auto STAGE_KV = [&](int kt, int buf) {
    const int kv0 = kt * 64;
#pragma unroll
    for (int i = 0; i < 4; ++i)
      async_copy16(Kl[i] + (size_t)kv0 * HD_,
                   (char*)Ks[buf] + (i * 256 + wbase) * 16);
#pragma unroll
    for (int i = 0; i < 4; ++i)
      async_copy16(Vl[i] + kv0, (char*)Vs[buf] + (i * 256 + wbase) * 16);
  };

  for (int half = 0; half < 2; ++half) {
    const int qt = half ? (15 - pid) : pid;
    const int q0 = qt * 128;
    const int qg = q0 + wid * 32 + l31;  // this lane's q-row

    STAGE_KV(0, 0);

    // ---- Q load + fused RoPE + QSCALE (overlaps tile-0 staging)
    bf16x8 qf[8];
    {
      const u16* qrow = Qb + ((size_t)(b * H_ + h) * S_ + qg) * HD_ + hi * 8;
      const float* cb = fc + qg * 64 + hi * 4;
      const float* sb = fs + qg * 64 + hi * 4;
#pragma unroll
      for (int ks = 0; ks < 8; ++ks) {
        u16x8 v = *(const u16x8*)(qrow + ks * 16);
        float4 cv = *(const float4*)(cb + ks * 8);
        float4 sv = *(const float4*)(sb + ks * 8);
        unsigned w[4];
#pragma unroll
        for (int j = 0; j < 4; ++j) {
          float c = ((const float*)&cv)[j] * QSCALE_;
          float s = ((const float*)&sv)[j] * QSCALE_;
          float re = b2f((u16)v[2 * j]), im = b2f((u16)v[2 * j + 1]);
          w[j] = cvt_pk_bf16(re * c - im * s, re * s + im * c);
        }
        union { unsigned u[4]; bf16x8 q; } cvt;
        cvt.u[0] = w[0]; cvt.u[1] = w[1]; cvt.u[2] = w[2]; cvt.u[3] = w[3];
        qf[ks] = cvt.q;
      }
    }

    f32x16 oacc[4];
#pragma unroll
    for (int i = 0; i < 4; ++i)
#pragma unroll
      for (int j = 0; j < 16; ++j) oacc[i][j] = 0.f;
    float mrow = -3e38f, lrow = 0.f;

    __syncthreads();  // tile 0 landed + all waves ready

    const int nkt = 2 * qt + 2;
    for (int kt = 0; kt < nkt; ++kt) {
      const int cur = kt & 1;
      if (kt + 1 < nkt) STAGE_KV(kt + 1, cur ^ 1);  // prefetch next tile
      const char* Kc = (const char*)Ks[cur];
      const char* Vc = (const char*)Vs[cur];
      const int kv0 = kt * 64;

      // ---- S^T = K Q^T  (2 kv-frags x 8 d-steps)
      f32x16 sacc[2];
#pragma unroll
      for (int kf = 0; kf < 2; ++kf)
#pragma unroll
        for (int j = 0; j < 16; ++j) sacc[kf][j] = 0.f;
#pragma unroll
      for (int ks = 0; ks < 8; ++ks) {
#pragma unroll
        for (int kf = 0; kf < 2; ++kf) {
          const int arow = kf * 32 + l31;
          bf16x8 kfrag = *(const bf16x8*)(
              Kc + arow * 256 + ((((ks * 2 + hi) << 4)) ^ ((arow & 7) << 4)));
          sacc[kf] = __builtin_amdgcn_mfma_f32_32x32x16_bf16(kfrag, qf[ks],
                                                             sacc[kf], 0, 0, 0);
        }
      }

      // ---- causal mask (elementwise; wave-uniform condition)
      if (kv0 + 63 > q0 + wid * 32) {
#pragma unroll
        for (int kf = 0; kf < 2; ++kf)
#pragma unroll
          for (int r = 0; r < 16; ++r) {
            int kg = kv0 + kf * 32 + (r & 3) + 8 * (r >> 2) + 4 * hi;
            if (kg > qg) sacc[kf][r] = -3e38f;
          }
      }

      // ---- in-register online softmax (log2 domain), 4-way-ILP reductions
      float m0 = -3e38f, m1 = -3e38f, m2 = -3e38f, m3 = -3e38f;
#pragma unroll
      for (int kf = 0; kf < 2; ++kf)
#pragma unroll
        for (int r = 0; r < 4; ++r) {
          m0 = fmaxf(m0, sacc[kf][r]);
          m1 = fmaxf(m1, sacc[kf][r + 4]);
          m2 = fmaxf(m2, sacc[kf][r + 8]);
          m3 = fmaxf(m3, sacc[kf][r + 12]);
        }
      float rmax = fmaxf(fmaxf(m0, m1), fmaxf(m2, m3));
      rmax = fmaxf(rmax, __shfl_xor(rmax, 32, 64));
      const bool defer = __all(rmax - mrow <= 11.5f);
      float mnew, fsc;
      if (defer) {
        mnew = mrow; fsc = 1.0f;
      } else {
        mnew = fmaxf(mrow, rmax); fsc = exp2f(mrow - mnew);
      }
      mrow = mnew;
      float p0 = 0.f, p1 = 0.f, p2 = 0.f, p3 = 0.f;
#pragma unroll
      for (int kf = 0; kf < 2; ++kf)
#pragma unroll
        for (int r = 0; r < 4; ++r) {
          float e0 = exp2f(sacc[kf][r] - mnew);
          float e1 = exp2f(sacc[kf][r + 4] - mnew);
          float e2 = exp2f(sacc[kf][r + 8] - mnew);
          float e3 = exp2f(sacc[kf][r + 12] - mnew);
          sacc[kf][r] = e0; sacc[kf][r + 4] = e1;
          sacc[kf][r + 8] = e2; sacc[kf][r + 12] = e3;
          p0 += e0; p1 += e1; p2 += e2; p3 += e3;
        }
      float psum = (p0 + p1) + (p2 + p3);
      psum += __shfl_xor(psum, 32, 64);
      lrow = lrow * fsc + psum;

      if (!defer) {  // rare: redistribute fsc to O rows (q' = crow(r,hi))
#pragma unroll
        for (int r = 0; r < 16; ++r) {
          float fr = __shfl(fsc, (r & 3) + 8 * (r >> 2) + 4 * hi, 64);
#pragma unroll
          for (int df = 0; df < 4; ++df) oacc[df][r] *= fr;
        }
      }

      // ---- P -> registers: cvt_pk pairs + permlane32_swap -> A-frags
      bf16x8 pa[4];
#pragma unroll
      for (int kf = 0; kf < 2; ++kf) {
        unsigned w0 = cvt_pk_bf16(sacc[kf][0], sacc[kf][1]);
        unsigned w1 = cvt_pk_bf16(sacc[kf][2], sacc[kf][3]);
        unsigned w2 = cvt_pk_bf16(sacc[kf][4], sacc[kf][5]);
        unsigned w3 = cvt_pk_bf16(sacc[kf][6], sacc[kf][7]);
        unsigned w4 = cvt_pk_bf16(sacc[kf][8], sacc[kf][9]);
        unsigned w5 = cvt_pk_bf16(sacc[kf][10], sacc[kf][11]);
        unsigned w6 = cvt_pk_bf16(sacc[kf][12], sacc[kf][13]);
        unsigned w7 = cvt_pk_bf16(sacc[kf][14], sacc[kf][15]);
        asm volatile("v_permlane32_swap_b32 %0, %1" : "+v"(w0), "+v"(w2));
        asm volatile("v_permlane32_swap_b32 %0, %1" : "+v"(w1), "+v"(w3));
        asm volatile("v_permlane32_swap_b32 %0, %1" : "+v"(w4), "+v"(w6));
        asm volatile("v_permlane32_swap_b32 %0, %1" : "+v"(w5), "+v"(w7));
        union { unsigned u[4]; bf16x8 q; } f0, f1;
        f0.u[0] = w0; f0.u[1] = w1; f0.u[2] = w2; f0.u[3] = w3;
        f1.u[0] = w4; f1.u[1] = w5; f1.u[2] = w6; f1.u[3] = w7;
        pa[kf * 2] = f0.q;
        pa[kf * 2 + 1] = f1.q;
      }

      // ---- O += P @ V  (4 d-frags x 4 kv-steps)
#pragma unroll
      for (int ks = 0; ks < 4; ++ks) {
#pragma unroll
        for (int df = 0; df < 4; ++df) {
          const int vrow = df * 32 + l31;
          bf16x8 vf = *(const bf16x8*)(
              Vc + vrow * 128 + ((((ks * 2 + hi) << 4)) ^ ((vrow & 7) << 4)));
          oacc[df] = __builtin_amdgcn_mfma_f32_32x32x16_bf16(pa[ks], vf,
                                                             oacc[df], 0, 0, 0);
        }
      }
      __syncthreads();  // drains prefetch (overlapped by this tile's compute)
    }

    // ---- epilogue: O[q'][d = df*32+l31]
    const float linv = 1.f / lrow;
#pragma unroll
    for (int r = 0; r < 16; ++r) {
      const int qloc = (r & 3) + 8 * (r >> 2) + 4 * hi;
      const float invq = __shfl(linv, qloc, 64);
      const int sq = q0 + wid * 32 + qloc;
      u16* dst = AO + (size_t)(b * S_ + sq) * (H_ * HD_) + h * HD_ + l31;
#pragma unroll
      for (int df = 0; df < 4; ++df) dst[df * 32] = f2b(oacc[df][r] * invq);
    }
  }
}

// ---------------------------------------------------------------------------
extern "C" void kernel_launch(void* const* d_in, const int* in_sizes, int n_in,
                              void* d_out, int out_size, void* d_ws, size_t ws_size,
                              hipStream_t stream) {
  const float* x  = (const float*)d_in[0];
  const float* wq = (const float*)d_in[1];
  const float* wk = (const float*)d_in[2];
  const float* wv = (const float*)d_in[3];
  const float* wo = (const float*)d_in[4];
  const float* fc = (const float*)d_in[5];
  const float* fs = (const float*)d_in[6];
  float* out = (float*)d_out;

  // Workspace (u16 elements), 160 MiB total — same layout as R3-R11.
  u16* ws  = (u16*)d_ws;
  u16* wqT = ws;
  u16* VtB = ws;              // alias of wqT region (written after Q-proj reads wqT)
  u16* xb  = ws + 16777216;
  u16* AOb = xb;              // alias of xb region (after xb last use)
  u16* woT = ws + 33554432;
  u16* Qh  = ws + 50331648;
  u16* wkT = ws + 67108864;
  u16* wvT = ws + 71303168;
  u16* Kh  = ws + 75497472;

  dim3 blk(256);

  // One fused launch for all 5 independent prep ops
  prep_fused<<<dim3(26624), blk, 0, stream>>>(x, xb, wq, wqT, wk, wkT, wv, wvT,
                                              wo, woT);

  gemm256<1><<<dim3(16, 16), dim3(512), 0, stream>>>(xb, wqT, Qh, 4096, 4096, H_);
  // combined K+V projection; K -> Kh head-major, V -> VtB transposed
  gemm_kv<<<dim3(16, 32), blk, 0, stream>>>(xb, wkT, Kh, VtB, 4096, 2048, 4096);

  rope_bf16<<<dim3(8192), blk, 0, stream>>>((unsigned*)Kh, fc, fs, 2097152, 1.0f);

  attn_mfma<<<dim3(8, 32, 2), blk, 0, stream>>>(Qh, Kh, VtB, AOb, fc, fs);

  gemm256<0><<<dim3(16, 16), dim3(512), 0, stream>>>(AOb, woT, out, 4096, 4096, 0);
}

// Round 13
// 501.789 us; speedup vs baseline: 1.0409x; 1.0134x over previous
//
#include <hip/hip_runtime.h>
#include <math.h>

#define B_ 2
#define S_ 2048
#define DIM_ 4096
#define H_ 32
#define KV_ 8
#define HD_ 128
#define SCALE_ 0.08838834764831844f   // 128^-0.5
#define QSCALE_ 0.12751744154254998f  // SCALE_ * log2(e)

typedef unsigned short u16;
typedef __attribute__((ext_vector_type(8))) short bf16x8;
typedef __attribute__((ext_vector_type(4))) float f32x4;
typedef __attribute__((ext_vector_type(16))) float f32x16;
typedef __attribute__((ext_vector_type(8))) unsigned short u16x8;
typedef __attribute__((ext_vector_type(4))) unsigned short u16x4;

__device__ __forceinline__ u16 f2b(float f) {  // RNE f32->bf16
  union { float f; unsigned u; } v; v.f = f;
  unsigned r = v.u + 0x7fffu + ((v.u >> 16) & 1u);
  return (u16)(r >> 16);
}
__device__ __forceinline__ float b2f(u16 h) {
  union { unsigned u; float f; } v; v.u = ((unsigned)h) << 16;
  return v.f;
}
// HW packed f32->bf16 (RNE): lo -> bits[15:0], hi -> bits[31:16]
__device__ __forceinline__ unsigned cvt_pk_bf16(float lo, float hi) {
  unsigned r;
  asm("v_cvt_pk_bf16_f32 %0, %1, %2" : "=v"(r) : "v"(lo), "v"(hi));
  return r;
}
// Direct-to-LDS async copy, 16B/lane. LDS dest = wave-uniform base + lane*16.
__device__ __forceinline__ void async_copy16(const void* g, void* l) {
  __builtin_amdgcn_global_load_lds(
      (const __attribute__((address_space(1))) void*)g,
      (__attribute__((address_space(3))) void*)l, 16, 0, 0);
}
// Raw barrier WITH compiler memory fence (no vmcnt drain, unlike __syncthreads)
__device__ __forceinline__ void bar() {
  asm volatile("s_barrier" ::: "memory");
}

// ---------------------------------------------------------------------------
// Fused prep: ONE launch for {x->bf16 cvt, wq/wk/wv/wo transpose+cvt}.
// ---------------------------------------------------------------------------
__global__ __launch_bounds__(256) void prep_fused(
    const float* __restrict__ x, u16* __restrict__ xb,
    const float* __restrict__ wq, u16* __restrict__ wqT,
    const float* __restrict__ wk, u16* __restrict__ wkT,
    const float* __restrict__ wv, u16* __restrict__ wvT,
    const float* __restrict__ wo, u16* __restrict__ woT) {
  __shared__ float Ts[64][65];
  const int tid = threadIdx.x;
  const int bid = blockIdx.x;

  if (bid < 16384) {  // ---- bulk cvt: x (fp32) -> xb (bf16), float4/thread
    int i = bid * 256 + tid;
    float4 v = ((const float4*)x)[i];
    u16x4 o; o[0] = f2b(v.x); o[1] = f2b(v.y); o[2] = f2b(v.z); o[3] = f2b(v.w);
    ((u16x4*)xb)[i] = o;
    return;
  }

  // ---- transpose_cvt: W[K][N] fp32 -> WT[N][K] bf16, 64x64 tile
  const float* W; u16* WT; int K, N, gx, v;
  if (bid < 20480)      { W = wq; WT = wqT; K = DIM_; N = H_ * HD_;  gx = 64; v = bid - 16384; }
  else if (bid < 21504) { W = wk; WT = wkT; K = DIM_; N = KV_ * HD_; gx = 16; v = bid - 20480; }
  else if (bid < 22528) { W = wv; WT = wvT; K = DIM_; N = KV_ * HD_; gx = 16; v = bid - 21504; }
  else                  { W = wo; WT = woT; K = H_ * HD_; N = DIM_;  gx = 64; v = bid - 22528; }
  const int n0 = (v % gx) * 64, k0 = (v / gx) * 64;

#pragma unroll
  for (int p = 0; p < 4; ++p) {
    int r = p * 16 + (tid >> 4), c = (tid & 15) * 4;
    float4 w = *(const float4*)(W + (size_t)(k0 + r) * N + n0 + c);
    Ts[r][c] = w.x; Ts[r][c + 1] = w.y; Ts[r][c + 2] = w.z; Ts[r][c + 3] = w.w;
  }
  __syncthreads();
#pragma unroll
  for (int p = 0; p < 4; ++p) {
    int n = p * 16 + (tid >> 4), kq = (tid & 15) * 4;
    u16x4 o;
    o[0] = f2b(Ts[kq + 0][n]); o[1] = f2b(Ts[kq + 1][n]);
    o[2] = f2b(Ts[kq + 2][n]); o[3] = f2b(Ts[kq + 3][n]);
    *(u16x4*)(WT + (size_t)(n0 + n) * K + k0 + kq) = o;
  }
}

// ---------------------------------------------------------------------------
// bf16 MFMA GEMM, m97 structure, XCD-swizzled. KV projection (N=2048):
// heads 0-7 -> K head-major [b,kv,s,d] with FUSED RoPE (lane-pair shfl_xor:
// d parity = lane&1 since col0%128==0; hh block-uniform); heads 8-15 -> V
// written directly transposed to Vt [b,kv,d,s] (4 s-consec = 8B store).
// ---------------------------------------------------------------------------
__global__ __launch_bounds__(256) void gemm_kv(
    const u16* __restrict__ A, const u16* __restrict__ Bt,
    u16* __restrict__ Kh, u16* __restrict__ Vt,
    const float* __restrict__ fc, const float* __restrict__ fs,
    int M, int N, int K) {
  __shared__ u16 As[128 * 64];
  __shared__ u16 Bs[128 * 64];
  const int tid = threadIdx.x, lane = tid & 63;
  const int wbase = tid & ~63;
  const int o = blockIdx.y * gridDim.x + blockIdx.x;
  const int q8 = (gridDim.x * gridDim.y) >> 3;
  const int p = (o & 7) * q8 + (o >> 3);
  const int row0 = (p / gridDim.x) * 128, col0 = (p % gridDim.x) * 128;
  const int wm = ((tid >> 6) >> 1) * 64, wn = ((tid >> 6) & 1) * 64;

  f32x4 acc[4][4];
#pragma unroll
  for (int i = 0; i < 4; ++i)
#pragma unroll
    for (int j = 0; j < 4; ++j) acc[i][j] = (f32x4){0.f, 0.f, 0.f, 0.f};

  const int nk = K >> 6;
  for (int kt = 0; kt < nk; ++kt) {
    const int k0 = kt << 6;
#pragma unroll
    for (int i = 0; i < 4; ++i) {
      int g = i * 256 + tid;
      int r = g >> 3, ss = (g & 7) ^ (r & 7);
      async_copy16(A + (size_t)(row0 + r) * K + k0 + ss * 8,
                   (char*)As + (i * 256 + wbase) * 16);
    }
#pragma unroll
    for (int i = 0; i < 4; ++i) {
      int g = i * 256 + tid;
      int r = g >> 3, ss = (g & 7) ^ (r & 7);
      async_copy16(Bt + (size_t)(col0 + r) * K + k0 + ss * 8,
                   (char*)Bs + (i * 256 + wbase) * 16);
    }
    __syncthreads();
#pragma unroll
    for (int ks = 0; ks < 2; ++ks) {
      bf16x8 af[4], bf[4];
#pragma unroll
      for (int mi = 0; mi < 4; ++mi) {
        int r = wm + mi * 16 + (lane & 15);
        int off = (ks * 64 + ((lane >> 4) << 4)) ^ ((r & 7) << 4);
        af[mi] = *(const bf16x8*)((const char*)As + r * 128 + off);
      }
#pragma unroll
      for (int ni = 0; ni < 4; ++ni) {
        int r = wn + ni * 16 + (lane & 15);
        int off = (ks * 64 + ((lane >> 4) << 4)) ^ ((r & 7) << 4);
        bf[ni] = *(const bf16x8*)((const char*)Bs + r * 128 + off);
      }
#pragma unroll
      for (int mi = 0; mi < 4; ++mi)
#pragma unroll
        for (int ni = 0; ni < 4; ++ni)
          acc[mi][ni] = __builtin_amdgcn_mfma_f32_16x16x32_bf16(
              af[mi], bf[ni], acc[mi][ni], 0, 0, 0);
    }
    __syncthreads();
  }

  const bool isK = (col0 >> 7) < 8;  // block-uniform: hh = col0/128
#pragma unroll
  for (int mi = 0; mi < 4; ++mi)
#pragma unroll
    for (int ni = 0; ni < 4; ++ni) {
      const int mb = row0 + wm + mi * 16 + ((lane >> 4) << 2);
      const int n = col0 + wn + ni * 16 + (lane & 15);
      const int b = mb >> 11, s0 = mb & (S_ - 1);  // mb%4==0 -> same b for r=0..3
      const int hh = n >> 7, d = n & (HD_ - 1);
      if (isK) {  // K: head-major [b,kv,s,d] + fused RoPE
        const int ii = d >> 1;
        const bool odd = d & 1;
#pragma unroll
        for (int r = 0; r < 4; ++r) {
          float mine = acc[mi][ni][r];
          float other = __shfl_xor(mine, 1, 64);
          float c = fc[(s0 + r) * 64 + ii];
          float sn = fs[(s0 + r) * 64 + ii];
          // even d: out_re = re*c - im*sn (re=mine, im=other)
          // odd  d: out_im = re*sn + im*c (re=other, im=mine)
          float outv = odd ? (other * sn + mine * c) : (mine * c - other * sn);
          Kh[(((size_t)(b * 8 + hh)) * S_ + s0 + r) * HD_ + d] = f2b(outv);
        }
      } else {  // V: transposed [b,kv,d,s] — 4 consecutive s = 8B store
        u16x4 ov;
#pragma unroll
        for (int r = 0; r < 4; ++r) ov[r] = f2b(acc[mi][ni][r]);
        *(u16x4*)(Vt + (((size_t)(b * 8 + (hh & 7)) * HD_ + d) * S_ + s0)) = ov;
      }
    }
}

// ---------------------------------------------------------------------------
// 256x256 8-phase bf16 MFMA GEMM (R10 schedule — reverted exactly; frozen).
// ---------------------------------------------------------------------------
template <int OUT_MODE>
__global__ __launch_bounds__(512) void gemm256(
    const u16* __restrict__ A, const u16* __restrict__ Bt,
    void* __restrict__ Cout, int M, int N, int K, int heads) {
  __shared__ u16 lds[65536];  // A: bytes [0,65536), B: [65536,131072)
  char* const ldsb = (char*)lds;
  const int tid = threadIdx.x, lane = tid & 63, wid = tid >> 6;
  const int q = lane & 15, g = lane >> 4;
  const int wm = wid >> 2, wn = wid & 3;
  const int o = blockIdx.y * gridDim.x + blockIdx.x;
  const int q8 = (gridDim.x * gridDim.y) >> 3;
  const int p = (o & 7) * q8 + (o >> 3);
  const int row0 = (p / gridDim.x) * 256, col0 = (p % gridDim.x) * 256;
  const int nk = K >> 6, nh = nk << 2;

  const u16* srcA[2];
  const u16* srcB[2];
#pragma unroll
  for (int u = 0; u < 2; ++u) {
    int j = u * 512 + tid;
    int row = ((j >> 3) << 1) + ((j >> 2) & 1);
    int colg = (j & 3) ^ ((j >> 3) & 3);
    srcA[u] = A + (size_t)(row0 + row) * K + colg * 8;
    srcB[u] = Bt + (size_t)(col0 + row) * K + colg * 8;
  }

  auto STAGE = [&](int h) {
    if (h >= nh) return;
    int tau = h >> 2, ks = (h >> 1) & 1, op = h & 1;
    int slot = (2 * tau + ks) & 3;
    int koff = tau * 64 + ks * 32;
    char* lbase = ldsb + op * 65536 + slot * 16384 + wid * 1024;
#pragma unroll
    for (int u = 0; u < 2; ++u)
      async_copy16((op ? srcB[u] : srcA[u]) + koff, lbase + u * 8192);
  };

  int aread[8], bread[4];
#pragma unroll
  for (int mi = 0; mi < 8; ++mi) {
    int row = wm * 128 + mi * 16 + q;
    aread[mi] = (row >> 1) * 128 + (row & 1) * 64 + ((g ^ ((row >> 1) & 3)) << 4);
  }
#pragma unroll
  for (int ni = 0; ni < 4; ++ni) {
    int row = wn * 64 + ni * 16 + q;
    bread[ni] = (row >> 1) * 128 + (row & 1) * 64 + ((g ^ ((row >> 1) & 3)) << 4);
  }

  f32x4 acc[8][4];
#pragma unroll
  for (int i = 0; i < 8; ++i)
#pragma unroll
    for (int j = 0; j < 4; ++j) acc[i][j] = (f32x4){0.f, 0.f, 0.f, 0.f};

  auto RDA = [&](bf16x8* d, const char* s, int ob) {
#pragma unroll
    for (int i = 0; i < 4; ++i) d[i] = *(const bf16x8*)(s + aread[ob + i]);
  };
  auto RDB = [&](bf16x8* d, const char* s) {
#pragma unroll
    for (int i = 0; i < 4; ++i) d[i] = *(const bf16x8*)(s + bread[i]);
  };
  auto MFMA16 = [&](int mo, bf16x8* af, bf16x8* bfr) {
    __builtin_amdgcn_s_setprio(1);
#pragma unroll
    for (int mi = 0; mi < 4; ++mi)
#pragma unroll
      for (int ni = 0; ni < 4; ++ni)
        acc[mo + mi][ni] = __builtin_amdgcn_mfma_f32_16x16x32_bf16(
            af[mi], bfr[ni], acc[mo + mi][ni], 0, 0, 0);
    __builtin_amdgcn_s_setprio(0);
  };

#pragma unroll
  for (int h = 0; h < 6; ++h) STAGE(h);
  asm volatile("s_waitcnt vmcnt(4)" ::: "memory");
  bar();
  bf16x8 afc[4], afn[4], bfc[4], bfn[4];
  RDA(afc, ldsb, 0);
  RDB(bfc, ldsb + 65536);

  for (int t = 0; t < nk; ++t) {
    const int s0 = (2 * t) & 3, s1 = (2 * t + 1) & 3;
    const char* As0 = ldsb + s0 * 16384;
    const char* Bs1 = ldsb + 65536 + s1 * 16384;
    const char* As1 = ldsb + s1 * 16384;

    STAGE(4 * t + 6);
    bar();
    MFMA16(0, afc, bfc);
    RDA(afn, As0, 4);
    bar();

    STAGE(4 * t + 7);
    bar();
    MFMA16(4, afn, bfc);
    RDA(afc, As1, 0);
    RDB(bfn, Bs1);
    bar();

    STAGE(4 * t + 8);
    bar();
    MFMA16(0, afc, bfn);
    RDA(afn, As1, 4);
    bar();

    STAGE(4 * t + 9);
    bar();
    MFMA16(4, afn, bfn);
    if (t < nk - 2)
      asm volatile("s_waitcnt vmcnt(4)" ::: "memory");
    else if (t == nk - 2)
      asm volatile("s_waitcnt vmcnt(0)" ::: "memory");
    if (t < nk - 1) {
      const char* As0n = ldsb + ((2 * t + 2) & 3) * 16384;
      const char* Bs0n = ldsb + 65536 + ((2 * t + 2) & 3) * 16384;
      RDA(afc, As0n, 0);
      RDB(bfc, Bs0n);
    }
    bar();
  }

#pragma unroll
  for (int mi = 0; mi < 8; ++mi)
#pragma unroll
    for (int ni = 0; ni < 4; ++ni) {
      int mb = row0 + wm * 128 + mi * 16 + (g << 2);
      int n = col0 + wn * 64 + ni * 16 + q;
#pragma unroll
      for (int r = 0; r < 4; ++r) {
        int m = mb + r;
        float v = acc[mi][ni][r];
        if (OUT_MODE == 0) {
          ((float*)Cout)[(size_t)m * N + n] = v;
        } else {
          int b = m >> 11, s = m & (S_ - 1);
          int h = n >> 7, d = n & (HD_ - 1);
          ((u16*)Cout)[(((size_t)(b * heads + h)) * S_ + s) * HD_ + d] = f2b(v);
        }
      }
    }
}

// ---------------------------------------------------------------------------
// Flash attention, 32x32x16 MFMA + dbuf K/V prefetch + 4-way-ILP softmax.
// (unchanged from R12 — verified; no setprio, m190 lockstep regime)
// ---------------------------------------------------------------------------
__global__ __launch_bounds__(256, 2) void attn_mfma(
    const u16* __restrict__ Qb, const u16* __restrict__ Kb,
    const u16* __restrict__ Vt, u16* __restrict__ AO,
    const float* __restrict__ fc, const float* __restrict__ fs) {
  __shared__ u16 Ks[2][64 * 128];  // [kv][d] 256B rows, swizzled
  __shared__ u16 Vs[2][128 * 64];  // [d][kv] 128B rows, swizzled

  const int tid = threadIdx.x, lane = tid & 63, wid = tid >> 6;
  const int wbase = tid & ~63;
  const int o = blockIdx.x + (blockIdx.y << 3) + (blockIdx.z << 8);
  const int pid = o >> 6, h = o & 31, b = (o >> 5) & 1;
  const int kvh = h >> 2;
  const int l31 = lane & 31, hi = lane >> 5;

  const u16* Kbase = Kb + ((size_t)(b * KV_ + kvh) * S_) * HD_;
  const u16* Vbase = Vt + ((size_t)(b * KV_ + kvh) * HD_) * S_;

  const u16* Kl[4];
  const u16* Vl[4];
#pragma unroll
  for (int i = 0; i < 4; ++i) {
    int gg = i * 256 + tid;
    int rK = gg >> 4, ssK = (gg & 15) ^ (rK & 7);
    Kl[i] = Kbase + (size_t)rK * HD_ + ssK * 8;
    int rV = gg >> 3, ssV = (gg & 7) ^ (rV & 7);
    Vl[i] = Vbase + (size_t)rV * S_ + ssV * 8;
  }

  auto STAGE_KV = [&](int kt, int buf) {
    const int kv0 = kt * 64;
#pragma unroll
    for (int i = 0; i < 4; ++i)
      async_copy16(Kl[i] + (size_t)kv0 * HD_,
                   (char*)Ks[buf] + (i * 256 + wbase) * 16);
#pragma unroll
    for (int i = 0; i < 4; ++i)
      async_copy16(Vl[i] + kv0, (char*)Vs[buf] + (i * 256 + wbase) * 16);
  };

  for (int half = 0; half < 2; ++half) {
    const int qt = half ? (15 - pid) : pid;
    const int q0 = qt * 128;
    const int qg = q0 + wid * 32 + l31;  // this lane's q-row

    STAGE_KV(0, 0);

    // ---- Q load + fused RoPE + QSCALE (overlaps tile-0 staging)
    bf16x8 qf[8];
    {
      const u16* qrow = Qb + ((size_t)(b * H_ + h) * S_ + qg) * HD_ + hi * 8;
      const float* cb = fc + qg * 64 + hi * 4;
      const float* sb = fs + qg * 64 + hi * 4;
#pragma unroll
      for (int ks = 0; ks < 8; ++ks) {
        u16x8 v = *(const u16x8*)(qrow + ks * 16);
        float4 cv = *(const float4*)(cb + ks * 8);
        float4 sv = *(const float4*)(sb + ks * 8);
        unsigned w[4];
#pragma unroll
        for (int j = 0; j < 4; ++j) {
          float c = ((const float*)&cv)[j] * QSCALE_;
          float s = ((const float*)&sv)[j] * QSCALE_;
          float re = b2f((u16)v[2 * j]), im = b2f((u16)v[2 * j + 1]);
          w[j] = cvt_pk_bf16(re * c - im * s, re * s + im * c);
        }
        union { unsigned u[4]; bf16x8 q; } cvt;
        cvt.u[0] = w[0]; cvt.u[1] = w[1]; cvt.u[2] = w[2]; cvt.u[3] = w[3];
        qf[ks] = cvt.q;
      }
    }

    f32x16 oacc[4];
#pragma unroll
    for (int i = 0; i < 4; ++i)
#pragma unroll
      for (int j = 0; j < 16; ++j) oacc[i][j] = 0.f;
    float mrow = -3e38f, lrow = 0.f;

    __syncthreads();  // tile 0 landed + all waves ready

    const int nkt = 2 * qt + 2;
    for (int kt = 0; kt < nkt; ++kt) {
      const int cur = kt & 1;
      if (kt + 1 < nkt) STAGE_KV(kt + 1, cur ^ 1);  // prefetch next tile
      const char* Kc = (const char*)Ks[cur];
      const char* Vc = (const char*)Vs[cur];
      const int kv0 = kt * 64;

      // ---- S^T = K Q^T  (2 kv-frags x 8 d-steps)
      f32x16 sacc[2];
#pragma unroll
      for (int kf = 0; kf < 2; ++kf)
#pragma unroll
        for (int j = 0; j < 16; ++j) sacc[kf][j] = 0.f;
#pragma unroll
      for (int ks = 0; ks < 8; ++ks) {
#pragma unroll
        for (int kf = 0; kf < 2; ++kf) {
          const int arow = kf * 32 + l31;
          bf16x8 kfrag = *(const bf16x8*)(
              Kc + arow * 256 + ((((ks * 2 + hi) << 4)) ^ ((arow & 7) << 4)));
          sacc[kf] = __builtin_amdgcn_mfma_f32_32x32x16_bf16(kfrag, qf[ks],
                                                             sacc[kf], 0, 0, 0);
        }
      }

      // ---- causal mask (elementwise; wave-uniform condition)
      if (kv0 + 63 > q0 + wid * 32) {
#pragma unroll
        for (int kf = 0; kf < 2; ++kf)
#pragma unroll
          for (int r = 0; r < 16; ++r) {
            int kg = kv0 + kf * 32 + (r & 3) + 8 * (r >> 2) + 4 * hi;
            if (kg > qg) sacc[kf][r] = -3e38f;
          }
      }

      // ---- in-register online softmax (log2 domain), 4-way-ILP reductions
      float m0 = -3e38f, m1 = -3e38f, m2 = -3e38f, m3 = -3e38f;
#pragma unroll
      for (int kf = 0; kf < 2; ++kf)
#pragma unroll
        for (int r = 0; r < 4; ++r) {
          m0 = fmaxf(m0, sacc[kf][r]);
          m1 = fmaxf(m1, sacc[kf][r + 4]);
          m2 = fmaxf(m2, sacc[kf][r + 8]);
          m3 = fmaxf(m3, sacc[kf][r + 12]);
        }
      float rmax = fmaxf(fmaxf(m0, m1), fmaxf(m2, m3));
      rmax = fmaxf(rmax, __shfl_xor(rmax, 32, 64));
      const bool defer = __all(rmax - mrow <= 11.5f);
      float mnew, fsc;
      if (defer) {
        mnew = mrow; fsc = 1.0f;
      } else {
        mnew = fmaxf(mrow, rmax); fsc = exp2f(mrow - mnew);
      }
      mrow = mnew;
      float p0 = 0.f, p1 = 0.f, p2 = 0.f, p3 = 0.f;
#pragma unroll
      for (int kf = 0; kf < 2; ++kf)
#pragma unroll
        for (int r = 0; r < 4; ++r) {
          float e0 = exp2f(sacc[kf][r] - mnew);
          float e1 = exp2f(sacc[kf][r + 4] - mnew);
          float e2 = exp2f(sacc[kf][r + 8] - mnew);
          float e3 = exp2f(sacc[kf][r + 12] - mnew);
          sacc[kf][r] = e0; sacc[kf][r + 4] = e1;
          sacc[kf][r + 8] = e2; sacc[kf][r + 12] = e3;
          p0 += e0; p1 += e1; p2 += e2; p3 += e3;
        }
      float psum = (p0 + p1) + (p2 + p3);
      psum += __shfl_xor(psum, 32, 64);
      lrow = lrow * fsc + psum;

      if (!defer) {  // rare: redistribute fsc to O rows (q' = crow(r,hi))
#pragma unroll
        for (int r = 0; r < 16; ++r) {
          float fr = __shfl(fsc, (r & 3) + 8 * (r >> 2) + 4 * hi, 64);
#pragma unroll
          for (int df = 0; df < 4; ++df) oacc[df][r] *= fr;
        }
      }

      // ---- P -> registers: cvt_pk pairs + permlane32_swap -> A-frags
      bf16x8 pa[4];
#pragma unroll
      for (int kf = 0; kf < 2; ++kf) {
        unsigned w0 = cvt_pk_bf16(sacc[kf][0], sacc[kf][1]);
        unsigned w1 = cvt_pk_bf16(sacc[kf][2], sacc[kf][3]);
        unsigned w2 = cvt_pk_bf16(sacc[kf][4], sacc[kf][5]);
        unsigned w3 = cvt_pk_bf16(sacc[kf][6], sacc[kf][7]);
        unsigned w4 = cvt_pk_bf16(sacc[kf][8], sacc[kf][9]);
        unsigned w5 = cvt_pk_bf16(sacc[kf][10], sacc[kf][11]);
        unsigned w6 = cvt_pk_bf16(sacc[kf][12], sacc[kf][13]);
        unsigned w7 = cvt_pk_bf16(sacc[kf][14], sacc[kf][15]);
        asm volatile("v_permlane32_swap_b32 %0, %1" : "+v"(w0), "+v"(w2));
        asm volatile("v_permlane32_swap_b32 %0, %1" : "+v"(w1), "+v"(w3));
        asm volatile("v_permlane32_swap_b32 %0, %1" : "+v"(w4), "+v"(w6));
        asm volatile("v_permlane32_swap_b32 %0, %1" : "+v"(w5), "+v"(w7));
        union { unsigned u[4]; bf16x8 q; } f0, f1;
        f0.u[0] = w0; f0.u[1] = w1; f0.u[2] = w2; f0.u[3] = w3;
        f1.u[0] = w4; f1.u[1] = w5; f1.u[2] = w6; f1.u[3] = w7;
        pa[kf * 2] = f0.q;
        pa[kf * 2 + 1] = f1.q;
      }

      // ---- O += P @ V  (4 d-frags x 4 kv-steps)
#pragma unroll
      for (int ks = 0; ks < 4; ++ks) {
#pragma unroll
        for (int df = 0; df < 4; ++df) {
          const int vrow = df * 32 + l31;
          bf16x8 vf = *(const bf16x8*)(
              Vc + vrow * 128 + ((((ks * 2 + hi) << 4)) ^ ((vrow & 7) << 4)));
          oacc[df] = __builtin_amdgcn_mfma_f32_32x32x16_bf16(pa[ks], vf,
                                                             oacc[df], 0, 0, 0);
        }
      }
      __syncthreads();  // drains prefetch (overlapped by this tile's compute)
    }

    // ---- epilogue: O[q'][d = df*32+l31]
    const float linv = 1.f / lrow;
#pragma unroll
    for (int r = 0; r < 16; ++r) {
      const int qloc = (r & 3) + 8 * (r >> 2) + 4 * hi;
      const float invq = __shfl(linv, qloc, 64);
      const int sq = q0 + wid * 32 + qloc;
      u16* dst = AO + (size_t)(b * S_ + sq) * (H_ * HD_) + h * HD_ + l31;
#pragma unroll
      for (int df = 0; df < 4; ++df) dst[df * 32] = f2b(oacc[df][r] * invq);
    }
  }
}

// ---------------------------------------------------------------------------
extern "C" void kernel_launch(void* const* d_in, const int* in_sizes, int n_in,
                              void* d_out, int out_size, void* d_ws, size_t ws_size,
                              hipStream_t stream) {
  const float* x  = (const float*)d_in[0];
  const float* wq = (const float*)d_in[1];
  const float* wk = (const float*)d_in[2];
  const float* wv = (const float*)d_in[3];
  const float* wo = (const float*)d_in[4];
  const float* fc = (const float*)d_in[5];
  const float* fs = (const float*)d_in[6];
  float* out = (float*)d_out;

  // Workspace (u16 elements), 160 MiB total — same layout as R3-R12.
  u16* ws  = (u16*)d_ws;
  u16* wqT = ws;
  u16* VtB = ws;              // alias of wqT region (written after Q-proj reads wqT)
  u16* xb  = ws + 16777216;
  u16* AOb = xb;              // alias of xb region (after xb last use)
  u16* woT = ws + 33554432;
  u16* Qh  = ws + 50331648;
  u16* wkT = ws + 67108864;
  u16* wvT = ws + 71303168;
  u16* Kh  = ws + 75497472;

  dim3 blk(256);

  // One fused launch for all 5 independent prep ops
  prep_fused<<<dim3(26624), blk, 0, stream>>>(x, xb, wq, wqT, wk, wkT, wv, wvT,
                                              wo, woT);

  gemm256<1><<<dim3(16, 16), dim3(512), 0, stream>>>(xb, wqT, Qh, 4096, 4096, 4096, H_);
  // combined K+V projection; K -> Kh head-major with fused RoPE, V -> VtB transposed
  gemm_kv<<<dim3(16, 32), blk, 0, stream>>>(xb, wkT, Kh, VtB, fc, fs, 4096, 2048, 4096);

  attn_mfma<<<dim3(8, 32, 2), blk, 0, stream>>>(Qh, Kh, VtB, AOb, fc, fs);

  gemm256<0><<<dim3(16, 16), dim3(512), 0, stream>>>(AOb, woT, out, 4096, 4096, 4096, 0);
}